// Round 8
// baseline (135.683 us; speedup 1.0000x reference)
//
#include <hip/hip_runtime.h>

#define N_MICS  192
#define OVERLAP 1024
#define WINDOW  524288
#define ROWLEN  (OVERLAP + WINDOW)
#define BLK     256
#define SPT     4

#define RFL_I(x) __builtin_amdgcn_readfirstlane(x)
#define RFL_F(x) __uint_as_float(__builtin_amdgcn_readfirstlane(__float_as_uint(x)))

// 4-float vector with 4-byte alignment (dword-aligned global_load_dwordx4)
typedef float f4a4 __attribute__((ext_vector_type(4), aligned(4)));

// ---------------- delay preamble (exact f32 replication of numpy) ---------
__device__ __forceinline__ void compute_delays(
    const float* __restrict__ pos, const float* __restrict__ mic_pos,
    float* s_dist, int* s_off, float* s_df, int tid)
{
    if (tid < N_MICS) {
        float dx = __fsub_rn(pos[0], mic_pos[tid * 3 + 0]);
        float dy = __fsub_rn(pos[1], mic_pos[tid * 3 + 1]);
        float dz = __fsub_rn(pos[2], mic_pos[tid * 3 + 2]);
        float ss = __fadd_rn(__fadd_rn(__fmul_rn(dx, dx), __fmul_rn(dy, dy)),
                             __fmul_rn(dz, dz));
        s_dist[tid] = __fsqrt_rn(ss);
    }
    __syncthreads();
    if (tid < N_MICS) {
        float mx = s_dist[0];
        for (int i = 1; i < N_MICS; ++i) mx = fmaxf(mx, s_dist[i]);
        float dd = __fsub_rn(s_dist[tid], mx);              // <= 0
        float delay = __fmul_rn(
                          __fmul_rn(__fdiv_rn(-dd, 343000.0f), 768000.0f),
                          0.0625f);                         // /16 exact
        int di = (int)delay;                                // trunc, delay >= 0
        s_off[tid] = tid * ROWLEN + OVERLAP - di;
        s_df[tid]  = __fsub_rn(delay, (float)di);
    }
    __syncthreads();
}

// ---- main: R6 structure; vm1 via lane shuffle instead of strided gather --
__global__ __launch_bounds__(BLK) void tdbf_kernel(
    const float* __restrict__ pos,
    const float* __restrict__ mic_pos,
    const float* __restrict__ buf,
    float* __restrict__ out)
{
    __shared__ float s_dist[N_MICS];
    __shared__ int   s_off[N_MICS];
    __shared__ float s_df[N_MICS];
    const int tid = threadIdx.x;
    compute_delays(pos, mic_pos, s_dist, s_off, s_df, tid);

    const int lane = tid & 63;
    const int t4   = (blockIdx.x * BLK + tid) * SPT;
    float a0 = 0.f, a1 = 0.f, a2 = 0.f, a3 = 0.f;

    #pragma unroll 6
    for (int m = 0; m < N_MICS; ++m) {
        const int   off = RFL_I(s_off[m]);
        const float f   = RFL_F(s_df[m]);
        const float* p  = buf + off + t4;
        // one fully-dense 1024B wave load: lane i's 16B chunk abuts lane i+1's
        const f4a4  w   = *reinterpret_cast<const f4a4*>(p);
        // vm1 = previous sample = neighbor lane's w.w (same value as p[-1])
        float vm1 = __shfl_up(w.w, 1, 64);
        if (lane == 0) vm1 = p[-1];        // single-lane boundary load
        const float gg  = 1.0f - f;
        a0 = fmaf(w.x, gg, fmaf(vm1, f, a0));
        a1 = fmaf(w.y, gg, fmaf(w.x, f, a1));
        a2 = fmaf(w.z, gg, fmaf(w.y, f, a2));
        a3 = fmaf(w.w, gg, fmaf(w.z, f, a3));
    }

    const float inv = 1.0f / (float)N_MICS;
    float4 o; o.x = a0 * inv; o.y = a1 * inv; o.z = a2 * inv; o.w = a3 * inv;
    *reinterpret_cast<float4*>(out + t4) = o;   // t4 % 4 == 0 -> 16B aligned
}

extern "C" void kernel_launch(void* const* d_in, const int* in_sizes, int n_in,
                              void* d_out, int out_size, void* d_ws, size_t ws_size,
                              hipStream_t stream) {
    const float* pos     = (const float*)d_in[0];
    const float* mic_pos = (const float*)d_in[1];
    const float* buf     = (const float*)d_in[2];
    float* out           = (float*)d_out;

    dim3 grid(WINDOW / (BLK * SPT));   // 512 blocks
    dim3 block(BLK);
    tdbf_kernel<<<grid, block, 0, stream>>>(pos, mic_pos, buf, out);
}

// Round 9
// 76.508 us; speedup vs baseline: 1.7734x; 1.7734x over previous
//
#include <hip/hip_runtime.h>

#define N_MICS  192
#define OVERLAP 1024
#define WINDOW  524288
#define ROWLEN  (OVERLAP + WINDOW)
#define BLK     256
#define SPT     4
#define NXCD    8

#define RFL_I(x) __builtin_amdgcn_readfirstlane(x)
#define RFL_F(x) __uint_as_float(__builtin_amdgcn_readfirstlane(__float_as_uint(x)))

// 4-float vector with 4-byte alignment (dword-aligned global_load_dwordx4)
typedef float f4a4 __attribute__((ext_vector_type(4), aligned(4)));

// ---------------- delay preamble (exact f32 replication of numpy) ---------
__device__ __forceinline__ void compute_delays(
    const float* __restrict__ pos, const float* __restrict__ mic_pos,
    float* s_dist, int* s_off, float* s_df, int tid)
{
    if (tid < N_MICS) {
        float dx = __fsub_rn(pos[0], mic_pos[tid * 3 + 0]);
        float dy = __fsub_rn(pos[1], mic_pos[tid * 3 + 1]);
        float dz = __fsub_rn(pos[2], mic_pos[tid * 3 + 2]);
        float ss = __fadd_rn(__fadd_rn(__fmul_rn(dx, dx), __fmul_rn(dy, dy)),
                             __fmul_rn(dz, dz));
        s_dist[tid] = __fsqrt_rn(ss);
    }
    __syncthreads();
    if (tid < N_MICS) {
        float mx = s_dist[0];
        for (int i = 1; i < N_MICS; ++i) mx = fmaxf(mx, s_dist[i]);
        float dd = __fsub_rn(s_dist[tid], mx);              // <= 0
        float delay = __fmul_rn(
                          __fmul_rn(__fdiv_rn(-dd, 343000.0f), 768000.0f),
                          0.0625f);                         // /16 exact
        int di = (int)delay;                                // trunc, delay >= 0
        s_off[tid] = tid * ROWLEN + OVERLAP - di;
        s_df[tid]  = __fsub_rn(delay, (float)di);
    }
    __syncthreads();
}

// ---- main: R6 body + XCD-aware bijective block swizzle -------------------
// Default dispatch round-robins consecutive blocks across the 8 XCD L2s;
// swz gives each XCD 64 consecutive t-blocks (256KB contiguous per mic row)
// so span-boundary cache lines are fetched by exactly one XCD.
__global__ __launch_bounds__(BLK) void tdbf_kernel(
    const float* __restrict__ pos,
    const float* __restrict__ mic_pos,
    const float* __restrict__ buf,
    float* __restrict__ out)
{
    __shared__ float s_dist[N_MICS];
    __shared__ int   s_off[N_MICS];
    __shared__ float s_df[N_MICS];
    const int tid = threadIdx.x;
    compute_delays(pos, mic_pos, s_dist, s_off, s_df, tid);

    // bijective: 512 blocks = 8 XCDs x 64 contiguous chunks
    const int bid = (int)blockIdx.x;
    const int swz = (bid & (NXCD - 1)) * (512 / NXCD) + (bid >> 3);

    const int t4 = (swz * BLK + tid) * SPT;
    float a0 = 0.f, a1 = 0.f, a2 = 0.f, a3 = 0.f;

    #pragma unroll 6
    for (int m = 0; m < N_MICS; ++m) {
        const int   off = RFL_I(s_off[m]);
        const float f   = RFL_F(s_df[m]);
        const float* p  = buf + off + t4;
        const float vm1 = p[-1];
        const f4a4  w   = *reinterpret_cast<const f4a4*>(p);  // v0..v3, 1 instr
        const float gg  = 1.0f - f;
        a0 = fmaf(w.x, gg, fmaf(vm1, f, a0));
        a1 = fmaf(w.y, gg, fmaf(w.x, f, a1));
        a2 = fmaf(w.z, gg, fmaf(w.y, f, a2));
        a3 = fmaf(w.w, gg, fmaf(w.z, f, a3));
    }

    const float inv = 1.0f / (float)N_MICS;
    float4 o; o.x = a0 * inv; o.y = a1 * inv; o.z = a2 * inv; o.w = a3 * inv;
    *reinterpret_cast<float4*>(out + t4) = o;   // t4 % 4 == 0 -> 16B aligned
}

extern "C" void kernel_launch(void* const* d_in, const int* in_sizes, int n_in,
                              void* d_out, int out_size, void* d_ws, size_t ws_size,
                              hipStream_t stream) {
    const float* pos     = (const float*)d_in[0];
    const float* mic_pos = (const float*)d_in[1];
    const float* buf     = (const float*)d_in[2];
    float* out           = (float*)d_out;

    dim3 grid(WINDOW / (BLK * SPT));   // 512 blocks
    dim3 block(BLK);
    tdbf_kernel<<<grid, block, 0, stream>>>(pos, mic_pos, buf, out);
}